// Round 8
// baseline (563.913 us; speedup 1.0000x reference)
//
#include <hip/hip_runtime.h>
#include <math.h>

#define NN 50000
#define EE 600000
#define MOUT 10000
#define RUNCAP 256
#define NT4 (NN * 4)

typedef short bf16x8 __attribute__((ext_vector_type(8)));
typedef float f32x4 __attribute__((ext_vector_type(4)));

__device__ __forceinline__ unsigned short f2bf(float x) {
    unsigned int u = __float_as_uint(x);
    u = (u + 0x7FFFu + ((u >> 16) & 1u)) >> 16;
    return (unsigned short)u;
}
__device__ __forceinline__ float bf2f(unsigned int b) {
    return __uint_as_float(b << 16);
}

// ============ bf16 MFMA GEMM: C[M,NC] = A[M,K] @ Wt[NC,K]^T + bias ============
// mode 0: Cf = val (fp32)     mode 3: Cb = bf16(val)
__global__ __launch_bounds__(256) void gemm_bf16(
    const unsigned short* __restrict__ A, const unsigned short* __restrict__ Wt,
    const float* __restrict__ bias, float* __restrict__ Cf,
    unsigned short* __restrict__ Cb, int M, int K, int NC, int mode)
{
    __shared__ unsigned short As[128 * 40];
    __shared__ unsigned short Bs[128 * 40];
    const int t = threadIdx.x;
    const int wave = t >> 6, lane = t & 63;
    const int quad = lane >> 4, l16 = lane & 15;
    const int row0 = blockIdx.x * 128, col0 = blockIdx.y * 128;
    const int wr = (wave & 1) * 64, wc = (wave >> 1) * 64;
    const int sr = t >> 1, sc = (t & 1) * 16;
    const int grow = row0 + sr;
    const int nk = K >> 5;

    f32x4 acc[4][4];
    #pragma unroll
    for (int i = 0; i < 4; ++i)
        #pragma unroll
        for (int j = 0; j < 4; ++j)
            acc[i][j] = (f32x4){0.f, 0.f, 0.f, 0.f};

    uint4 av0 = make_uint4(0,0,0,0), av1 = av0, bv0, bv1;
    if (grow < M) {
        const uint4* ap = (const uint4*)(A + (size_t)grow * K + sc);
        av0 = ap[0]; av1 = ap[1];
    }
    {
        const uint4* bp = (const uint4*)(Wt + (size_t)(col0 + sr) * K + sc);
        bv0 = bp[0]; bv1 = bp[1];
    }

    for (int it = 0; it < nk; ++it) {
        __syncthreads();
        *(uint4*)(As + sr * 40 + sc)     = av0;
        *(uint4*)(As + sr * 40 + sc + 8) = av1;
        *(uint4*)(Bs + sr * 40 + sc)     = bv0;
        *(uint4*)(Bs + sr * 40 + sc + 8) = bv1;
        __syncthreads();
        if (it + 1 < nk) {
            int kb = (it + 1) * 32;
            if (grow < M) {
                const uint4* ap = (const uint4*)(A + (size_t)grow * K + kb + sc);
                av0 = ap[0]; av1 = ap[1];
            }
            const uint4* bp = (const uint4*)(Wt + (size_t)(col0 + sr) * K + kb + sc);
            bv0 = bp[0]; bv1 = bp[1];
        }
        bf16x8 af[4], bfr[4];
        #pragma unroll
        for (int f = 0; f < 4; ++f) {
            af[f]  = *(const bf16x8*)(As + (wr + f * 16 + l16) * 40 + quad * 8);
            bfr[f] = *(const bf16x8*)(Bs + (wc + f * 16 + l16) * 40 + quad * 8);
        }
        #pragma unroll
        for (int fr = 0; fr < 4; ++fr)
            #pragma unroll
            for (int fc = 0; fc < 4; ++fc)
                acc[fr][fc] = __builtin_amdgcn_mfma_f32_16x16x32_bf16(
                    af[fr], bfr[fc], acc[fr][fc], 0, 0, 0);
    }

    float b4[4];
    #pragma unroll
    for (int fc = 0; fc < 4; ++fc)
        b4[fc] = bias ? bias[col0 + wc + fc * 16 + l16] : 0.f;
    #pragma unroll
    for (int fr = 0; fr < 4; ++fr) {
        #pragma unroll
        for (int reg = 0; reg < 4; ++reg) {
            int row = row0 + wr + fr * 16 + quad * 4 + reg;
            if (row >= M) continue;
            #pragma unroll
            for (int fc = 0; fc < 4; ++fc) {
                int col = col0 + wc + fc * 16 + l16;
                size_t ci = (size_t)row * NC + col;
                float val = acc[fr][fc][reg] + b4[fc];
                if (mode == 0) Cf[ci] = val;
                else           Cb[ci] = f2bf(val);
            }
        }
    }
}

// ============ fused MLP: C = gate*( gelu(A@W3t^T) @ AWt^T + a_b ) + (1-gate)*hres ============
__global__ __launch_bounds__(256) void mlp_kernel(
    const unsigned short* __restrict__ A, const unsigned short* __restrict__ W3t,
    const unsigned short* __restrict__ AWt, const float* __restrict__ a_bias,
    const float* __restrict__ skipv, const float* __restrict__ hres,
    const int* __restrict__ rowmap, float* __restrict__ Cf,
    unsigned short* __restrict__ Cb, int M)
{
    __shared__ unsigned short As[128 * 40];
    __shared__ unsigned short Bs[128 * 40];
    __shared__ unsigned short msgS[128 * 136];
    const int t = threadIdx.x;
    const int wave = t >> 6, lane = t & 63;
    const int quad = lane >> 4, l16 = lane & 15;
    const int row0 = blockIdx.x * 128;
    const int wr = (wave & 1) * 64, wc = (wave >> 1) * 64;
    const int sr = t >> 1, sc = (t & 1) * 16;
    const int grow = row0 + sr;
    int arow = 0;
    bool rvalid = grow < M;
    if (rvalid) arow = rowmap ? rowmap[grow] : grow;

    f32x4 acc[4][4];
    #pragma unroll
    for (int i = 0; i < 4; ++i)
        #pragma unroll
        for (int j = 0; j < 4; ++j)
            acc[i][j] = (f32x4){0.f, 0.f, 0.f, 0.f};

    uint4 av0 = make_uint4(0,0,0,0), av1 = av0, bv0, bv1;
    if (rvalid) {
        const uint4* ap = (const uint4*)(A + (size_t)arow * 512 + sc);
        av0 = ap[0]; av1 = ap[1];
    }
    {
        const uint4* bp = (const uint4*)(W3t + (size_t)sr * 512 + sc);
        bv0 = bp[0]; bv1 = bp[1];
    }

    for (int it = 0; it < 16; ++it) {           // K = 512
        __syncthreads();
        *(uint4*)(As + sr * 40 + sc)     = av0;
        *(uint4*)(As + sr * 40 + sc + 8) = av1;
        *(uint4*)(Bs + sr * 40 + sc)     = bv0;
        *(uint4*)(Bs + sr * 40 + sc + 8) = bv1;
        __syncthreads();
        if (it + 1 < 16) {
            int kb = (it + 1) * 32;
            if (rvalid) {
                const uint4* ap = (const uint4*)(A + (size_t)arow * 512 + kb + sc);
                av0 = ap[0]; av1 = ap[1];
            }
            const uint4* bp = (const uint4*)(W3t + (size_t)sr * 512 + kb + sc);
            bv0 = bp[0]; bv1 = bp[1];
        }
        bf16x8 af[4], bfr[4];
        #pragma unroll
        for (int f = 0; f < 4; ++f) {
            af[f]  = *(const bf16x8*)(As + (wr + f * 16 + l16) * 40 + quad * 8);
            bfr[f] = *(const bf16x8*)(Bs + (wc + f * 16 + l16) * 40 + quad * 8);
        }
        #pragma unroll
        for (int fr = 0; fr < 4; ++fr)
            #pragma unroll
            for (int fc = 0; fc < 4; ++fc)
                acc[fr][fc] = __builtin_amdgcn_mfma_f32_16x16x32_bf16(
                    af[fr], bfr[fc], acc[fr][fc], 0, 0, 0);
    }

    // gelu -> msgS (bf16)
    #pragma unroll
    for (int fr = 0; fr < 4; ++fr)
        #pragma unroll
        for (int reg = 0; reg < 4; ++reg) {
            int rl = wr + fr * 16 + quad * 4 + reg;
            #pragma unroll
            for (int fc = 0; fc < 4; ++fc) {
                int col = wc + fc * 16 + l16;
                float v = acc[fr][fc][reg];
                float gl = 0.5f * v * (1.f + erff(v * 0.70710678118654752f));
                msgS[rl * 136 + col] = f2bf(gl);
            }
        }

    // stage 2: K = 128 from msgS, B = AWt
    f32x4 acc2[4][4];
    #pragma unroll
    for (int i = 0; i < 4; ++i)
        #pragma unroll
        for (int j = 0; j < 4; ++j)
            acc2[i][j] = (f32x4){0.f, 0.f, 0.f, 0.f};

    for (int it = 0; it < 4; ++it) {
        __syncthreads();
        const uint4* bp = (const uint4*)(AWt + (size_t)sr * 128 + it * 32 + sc);
        *(uint4*)(Bs + sr * 40 + sc)     = bp[0];
        *(uint4*)(Bs + sr * 40 + sc + 8) = bp[1];
        __syncthreads();
        bf16x8 af[4], bfr[4];
        #pragma unroll
        for (int f = 0; f < 4; ++f) {
            af[f]  = *(const bf16x8*)(msgS + (wr + f * 16 + l16) * 136 + it * 32 + quad * 8);
            bfr[f] = *(const bf16x8*)(Bs + (wc + f * 16 + l16) * 40 + quad * 8);
        }
        #pragma unroll
        for (int fr = 0; fr < 4; ++fr)
            #pragma unroll
            for (int fc = 0; fc < 4; ++fc)
                acc2[fr][fc] = __builtin_amdgcn_mfma_f32_16x16x32_bf16(
                    af[fr], bfr[fc], acc2[fr][fc], 0, 0, 0);
    }

    const float gate = 1.f / (1.f + __expf(-skipv[0]));
    float b4[4];
    #pragma unroll
    for (int fc = 0; fc < 4; ++fc) b4[fc] = a_bias[wc + fc * 16 + l16];
    #pragma unroll
    for (int fr = 0; fr < 4; ++fr) {
        #pragma unroll
        for (int reg = 0; reg < 4; ++reg) {
            int row = row0 + wr + fr * 16 + quad * 4 + reg;
            if (row >= M) continue;
            int hrow = rowmap ? rowmap[row] : row;
            #pragma unroll
            for (int fc = 0; fc < 4; ++fc) {
                int col = wc + fc * 16 + l16;
                float val = acc2[fr][fc][reg] + b4[fc];
                float nv = gate * val + (1.f - gate) * hres[(size_t)hrow * 128 + col];
                Cf[(size_t)row * 128 + col] = nv;
                if (Cb) Cb[(size_t)row * 128 + col] = f2bf(nv);
            }
        }
    }
}

// ============ merged weight prep + x cast ============
// qkv weight rows 512..767 PERMUTED for 8B kv gathers; qrel rows (0..511) are
// PRE-SCALED by p_rel[r,h]/sqrt(32) (score is linear in q_rel) so agg needs no scale.
__global__ __launch_bounds__(256) void prep_kernel(
    const float* __restrict__ proj_w, const float* __restrict__ a_w,
    const float* __restrict__ q_w, const float* __restrict__ q_b,
    const float* __restrict__ a_rel,
    const float* __restrict__ k_w, const float* __restrict__ k_b,
    const float* __restrict__ v_w, const float* __restrict__ v_b,
    const float* __restrict__ m_rel, const float* __restrict__ p_rel,
    const float* __restrict__ x,
    unsigned short* __restrict__ wt_pa, unsigned short* __restrict__ qkvw,
    float* __restrict__ fbias, unsigned short* __restrict__ msg_wt,
    unsigned short* __restrict__ x_bf)
{
    const int b = blockIdx.x, t = threadIdx.x;
    if (b < 192) {                       // proj^T, a_w0^T, a_w1^T
        int wi = b >> 6;
        int flat = (b & 63) * 256 + t;
        int n = flat >> 7, c = flat & 127;
        const float* src = (wi == 0) ? proj_w : (wi == 1) ? a_w : a_w + 16384;
        wt_pa[(size_t)wi * 16384 + n * 128 + c] = f2bf(src[c * 128 + n]);
    } else if (b < 960) {                // fused qkv weight [768][128] per layer
        int q = b - 192;
        int l = q >= 384 ? 1 : 0;
        int flat = (q - l * 384) * 256 + t;
        int nrow = flat >> 7, c = flat & 127;
        unsigned short* wt = qkvw + (size_t)l * 98304;
        float* fb = fbias + l * 768;
        if (nrow < 512) {
            int r = nrow >> 7, hh = (nrow >> 5) & 3, d = nrow & 31;
            float prl = p_rel[l * 16 + r * 4 + hh] * 0.17677669529663687f;
            const float* qwc = q_w + (size_t)l * 16384 + c * 128 + hh * 32;
            const float* ar  = a_rel + (size_t)(l * 4 + r) * 4096 + hh * 1024 + d * 32;
            float s = 0.f;
            #pragma unroll 8
            for (int e = 0; e < 32; ++e) s += qwc[e] * ar[e];
            wt[(size_t)nrow * 128 + c] = f2bf(s * prl);
            if (c == 0) {
                const float* qb = q_b + l * 128 + hh * 32;
                float bb = 0.f;
                #pragma unroll 8
                for (int e = 0; e < 32; ++e) bb += qb[e] * ar[e];
                fb[nrow] = bb * prl;
            }
        } else {                         // k/v interleaved rows
            int j = nrow - 512;
            int tt = j >> 2, s = j & 3;
            int col = 2 * tt + (s & 1);
            const float* w  = (s < 2) ? k_w : v_w;
            const float* bb = (s < 2) ? k_b : v_b;
            wt[(size_t)nrow * 128 + c] = f2bf(w[(size_t)l * 16384 + c * 128 + col]);
            if (c == 0) fb[nrow] = bb[l * 128 + col];
        }
    } else if (b < 1472) {               // msg weight [128][512] per layer
        int q = b - 960;
        int l = q >= 256 ? 1 : 0;
        int flat = (q - l * 256) * 256 + t;
        int n = flat >> 9, kk = flat & 511;
        int h = n >> 5, e = n & 31;
        int r = kk >> 7, h2 = (kk >> 5) & 3, d = kk & 31;
        float val = (h2 == h) ? m_rel[(size_t)(l * 4 + r) * 4096 + h * 1024 + d * 32 + e] : 0.f;
        msg_wt[(size_t)l * 65536 + (size_t)n * 512 + kk] = f2bf(val);
    } else {                             // cast x -> bf16
        int i = (b - 1472) * 256 + t;
        if (i < NN * 32) {
            float4 v = ((const float4*)x)[i];
            uint2 pk;
            pk.x = (unsigned int)f2bf(v.x) | ((unsigned int)f2bf(v.y) << 16);
            pk.y = (unsigned int)f2bf(v.z) | ((unsigned int)f2bf(v.w) << 16);
            ((uint2*)x_bf)[i] = pk;
        }
    }
}

// ============ BatchNorm ============
__global__ __launch_bounds__(128) void bn_stats_kernel(const float* __restrict__ h,
                                                       float* __restrict__ stats, int n)
{
    int c = threadIdx.x;
    int r0 = blockIdx.x * 128;
    int r1 = min(r0 + 128, n);
    float s = 0.f, s2 = 0.f;
    for (int r = r0; r < r1; ++r) {
        float v = h[(size_t)r * 128 + c];
        s += v; s2 += v * v;
    }
    atomicAdd(&stats[c], s);
    atomicAdd(&stats[128 + c], s2);
}

__global__ __launch_bounds__(256) void bn_apply_kernel(float* __restrict__ h,
    unsigned short* __restrict__ hbf, const float* __restrict__ stats,
    const float* __restrict__ gamma, const float* __restrict__ beta, int n)
{
    int i = blockIdx.x * 256 + threadIdx.x;
    if (i >= n * 32) return;
    int c4 = i & 31;
    float invN = 1.f / (float)n;
    float4 v = ((const float4*)h)[i];
    float o[4] = {v.x, v.y, v.z, v.w};
    #pragma unroll
    for (int j = 0; j < 4; ++j) {
        int c = c4 * 4 + j;
        float mu = stats[c] * invN;
        float var = stats[128 + c] * invN - mu * mu;
        o[j] = (o[j] - mu) * rsqrtf(var + 1e-5f) * gamma[c] + beta[c];
    }
    ((float4*)h)[i] = make_float4(o[0], o[1], o[2], o[3]);
    uint2 pk;
    pk.x = (unsigned int)f2bf(o[0]) | ((unsigned int)f2bf(o[1]) << 16);
    pk.y = (unsigned int)f2bf(o[2]) | ((unsigned int)f2bf(o[3]) << 16);
    ((uint2*)hbf)[i] = pk;
}

// ============ CSR build over N*4 segments ============
__global__ __launch_bounds__(256) void zero_csr_kernel(int* __restrict__ cnt,
                                                       float* __restrict__ stats)
{
    int i = blockIdx.x * 256 + threadIdx.x;
    if (i < NT4) cnt[i] = 0;
    if (i < 256) stats[i] = 0.f;
}

__global__ __launch_bounds__(256) void hist_kernel(const int* __restrict__ ei,
    const int* __restrict__ et, int* __restrict__ cnt, int E)
{
    int e = blockIdx.x * 256 + threadIdx.x;
    if (e < E) atomicAdd(&cnt[ei[E + e] * 4 + et[e]], 1);
}

__global__ __launch_bounds__(256) void scan_block_kernel(const int* __restrict__ cnt,
    int* __restrict__ excl, int* __restrict__ bsum, int n)
{
    __shared__ int tmp[256];
    int i = blockIdx.x * 256 + threadIdx.x;
    int v = (i < n) ? cnt[i] : 0;
    tmp[threadIdx.x] = v;
    __syncthreads();
    for (int ofs = 1; ofs < 256; ofs <<= 1) {
        int t = (threadIdx.x >= ofs) ? tmp[threadIdx.x - ofs] : 0;
        __syncthreads();
        tmp[threadIdx.x] += t;
        __syncthreads();
    }
    if (i < n) excl[i] = tmp[threadIdx.x] - v;
    if (threadIdx.x == 255) bsum[blockIdx.x] = tmp[255];
}

__global__ __launch_bounds__(256) void scan_bsum_multi(int* __restrict__ bsum, int nb)
{
    __shared__ int tmp[256];
    __shared__ int carry;
    if (threadIdx.x == 0) carry = 0;
    __syncthreads();
    for (int b0 = 0; b0 < nb; b0 += 256) {
        int i = b0 + threadIdx.x;
        int v = (i < nb) ? bsum[i] : 0;
        tmp[threadIdx.x] = v;
        __syncthreads();
        for (int ofs = 1; ofs < 256; ofs <<= 1) {
            int t = (threadIdx.x >= ofs) ? tmp[threadIdx.x - ofs] : 0;
            __syncthreads();
            tmp[threadIdx.x] += t;
            __syncthreads();
        }
        int excl = tmp[threadIdx.x] - v + carry;
        if (i < nb) bsum[i] = excl;
        __syncthreads();
        if (threadIdx.x == 255) carry += tmp[255];
        __syncthreads();
    }
}

__global__ __launch_bounds__(256) void scan_add_kernel(int* __restrict__ excl,
    const int* __restrict__ bsum, int* __restrict__ fill, int n, int total)
{
    int i = blockIdx.x * 256 + threadIdx.x;
    if (i < n) {
        int o = excl[i] + bsum[blockIdx.x];
        excl[i] = o;
        fill[i] = o;
    }
    if (blockIdx.x == 0 && threadIdx.x == 0) excl[n] = total;
}

__global__ __launch_bounds__(256) void scatter_kernel(const int* __restrict__ ei,
    const int* __restrict__ et, int* __restrict__ fill, int* __restrict__ pack, int E)
{
    int e = blockIdx.x * 256 + threadIdx.x;
    if (e >= E) return;
    int seg = ei[E + e] * 4 + et[e];
    int p = atomicAdd(&fill[seg], 1);
    pack[p] = ei[e];
}

// ============ fused attention: ONE WAVE PER (node, relation) RUN ============
// 4x TLP vs one-wave-per-node: each wave's serial chain is ~1 unroll group; latency
// hidden by resident waves. q pre-scaled by p_rel/sqrt(32) at prep. No barriers.
__global__ __launch_bounds__(256) void agg_fused_kernel(
    const unsigned short* __restrict__ qkv,
    const int* __restrict__ off4, const int* __restrict__ pack,
    unsigned short* __restrict__ aggb, int n)
{
    __shared__ int spack[4][RUNCAP];
    const int wv = threadIdx.x >> 6;
    const int lane = threadIdx.x & 63;
    const int unit = blockIdx.x * 4 + wv;      // (node, rel) flat index
    if (unit >= n * 4) return;
    const int node = unit >> 2, r = unit & 3;

    const int beg = __builtin_amdgcn_readfirstlane(off4[unit]);
    const int end = __builtin_amdgcn_readfirstlane(off4[unit + 1]);
    const int len = end - beg;

    unsigned int qu = *(const unsigned int*)(qkv + (size_t)node * 768 + (r * 64 + lane) * 2);
    float qx = bf2f(qu & 0xFFFFu);
    float qy = bf2f(qu >> 16);
    float den = 0.f, ax = 0.f, ay = 0.f;

    if (len <= RUNCAP) {
        for (int i = lane; i < len; i += 64) spack[wv][i] = pack[beg + i];
        asm volatile("s_waitcnt vmcnt(0) lgkmcnt(0)" ::: "memory");
        for (int i = 0; i < len; i += 4) {
            unsigned int ku[4], vu[4];
            #pragma unroll
            for (int j = 0; j < 4; ++j) {
                int ii = i + j; if (ii >= len) ii = len - 1;
                int src = spack[wv][ii];
                uint2 kv = *(const uint2*)(qkv + (size_t)src * 768 + 512 + lane * 4);
                ku[j] = kv.x; vu[j] = kv.y;
            }
            float p[4];
            #pragma unroll
            for (int j = 0; j < 4; ++j)
                p[j] = qx * bf2f(ku[j] & 0xFFFFu) + qy * bf2f(ku[j] >> 16);
            #pragma unroll
            for (int j = 0; j < 4; ++j) {
                p[j] += __shfl_xor(p[j], 1); p[j] += __shfl_xor(p[j], 2);
                p[j] += __shfl_xor(p[j], 4); p[j] += __shfl_xor(p[j], 8);
            }
            #pragma unroll
            for (int j = 0; j < 4; ++j) {
                float s = fminf(fmaxf(p[j], -80.f), 80.f);
                float e = __expf(s);
                if (i + j >= len) e = 0.f;
                den += e;
                ax += e * bf2f(vu[j] & 0xFFFFu);
                ay += e * bf2f(vu[j] >> 16);
            }
        }
    } else {   // giant-run fallback: stream pack scalar-wise
        for (int pp = beg; pp < end; ++pp) {
            int src = __builtin_amdgcn_readfirstlane(pack[pp]);
            uint2 kv = *(const uint2*)(qkv + (size_t)src * 768 + 512 + lane * 4);
            float p0 = qx * bf2f(kv.x & 0xFFFFu) + qy * bf2f(kv.x >> 16);
            p0 += __shfl_xor(p0, 1); p0 += __shfl_xor(p0, 2);
            p0 += __shfl_xor(p0, 4); p0 += __shfl_xor(p0, 8);
            float e = __expf(fminf(fmaxf(p0, -80.f), 80.f));
            den += e;
            ax += e * bf2f(kv.y & 0xFFFFu);
            ay += e * bf2f(kv.y >> 16);
        }
    }
    float inv = den > 0.f ? 1.f / den : 0.f;
    unsigned int ow = (unsigned int)f2bf(ax * inv) | ((unsigned int)f2bf(ay * inv) << 16);
    ((unsigned int*)(aggb + (size_t)node * 512))[r * 64 + lane] = ow;
}

extern "C" void kernel_launch(void* const* d_in, const int* in_sizes, int n_in,
                              void* d_out, int out_size, void* d_ws, size_t ws_size,
                              hipStream_t stream)
{
    const float* x      = (const float*)d_in[0];
    const float* proj_w = (const float*)d_in[1];
    const float* proj_b = (const float*)d_in[2];
    const float* bn_g   = (const float*)d_in[3];
    const float* bn_b   = (const float*)d_in[4];
    const float* q_w    = (const float*)d_in[5];
    const float* q_b    = (const float*)d_in[6];
    const float* k_w    = (const float*)d_in[7];
    const float* k_b    = (const float*)d_in[8];
    const float* v_w    = (const float*)d_in[9];
    const float* v_b    = (const float*)d_in[10];
    const float* a_w    = (const float*)d_in[11];
    const float* a_b    = (const float*)d_in[12];
    const float* skip   = (const float*)d_in[13];
    const float* a_rel  = (const float*)d_in[14];
    const float* m_rel  = (const float*)d_in[15];
    const float* p_rel  = (const float*)d_in[16];
    const int* edge_index = (const int*)d_in[17];
    const int* edge_type  = (const int*)d_in[18];
    const int* idx        = (const int*)d_in[19];
    float* out = (float*)d_out;

    const int N = NN, E = EE;
    float* ws = (float*)d_ws;
    size_t o = 0;
    float* h      = ws + o;  o += (size_t)N * 128;
    float* stats  = ws + o;  o += 256;
    float* fbias  = ws + o;  o += 2 * 768;
    int* cnt  = (int*)(ws + o); o += NT4;
    int* off4 = (int*)(ws + o); o += NT4 + 1;
    int* fill = (int*)(ws + o); o += NT4;
    int* bsum = (int*)(ws + o); o += 1024;
    int* pack = (int*)(ws + o); o += E;
    unsigned short* x_bf   = (unsigned short*)(ws + o); o += (size_t)N * 64;
    unsigned short* h_bf   = (unsigned short*)(ws + o); o += (size_t)N * 64;
    unsigned short* qkv_bf = (unsigned short*)(ws + o); o += (size_t)N * 384;
    unsigned short* agg_bf = (unsigned short*)(ws + o); o += (size_t)N * 256;
    unsigned short* wt_pa  = (unsigned short*)(ws + o); o += 3 * 16384 / 2;
    unsigned short* qkvw   = (unsigned short*)(ws + o); o += 2 * 98304 / 2;
    unsigned short* msg_wt = (unsigned short*)(ws + o); o += 2 * 65536 / 2;

    const int NB4 = (NT4 + 255) / 256;

    // ---- CSR build over (dst, rel) segments ----
    zero_csr_kernel<<<NB4, 256, 0, stream>>>(cnt, stats);
    hist_kernel<<<(E + 255) / 256, 256, 0, stream>>>(edge_index, edge_type, cnt, E);
    scan_block_kernel<<<NB4, 256, 0, stream>>>(cnt, off4, bsum, NT4);
    scan_bsum_multi<<<1, 256, 0, stream>>>(bsum, NB4);
    scan_add_kernel<<<NB4, 256, 0, stream>>>(off4, bsum, fill, NT4, E);
    scatter_kernel<<<(E + 255) / 256, 256, 0, stream>>>(edge_index, edge_type, fill, pack, E);

    // ---- weight prep + x cast (one launch) ----
    prep_kernel<<<1472 + (N * 32 + 255) / 256, 256, 0, stream>>>(
        proj_w, a_w, q_w, q_b, a_rel, k_w, k_b, v_w, v_b, m_rel, p_rel, x,
        wt_pa, qkvw, fbias, msg_wt, x_bf);

    // ---- proj + BN ----
    dim3 g128((N + 127) / 128, 1), g768((N + 127) / 128, 6);
    gemm_bf16<<<g128, 256, 0, stream>>>(x_bf, wt_pa, proj_b, h, nullptr, N, 128, 128, 0);
    bn_stats_kernel<<<(N + 127) / 128, 128, 0, stream>>>(h, stats, N);
    bn_apply_kernel<<<(N * 32 + 255) / 256, 256, 0, stream>>>(h, h_bf, stats, bn_g, bn_b, N);

    // ---- layer 0 ----
    gemm_bf16<<<g768, 256, 0, stream>>>(h_bf, qkvw, fbias, nullptr, qkv_bf, N, 128, 768, 3);
    agg_fused_kernel<<<N, 256, 0, stream>>>(qkv_bf, off4, pack, agg_bf, N);
    mlp_kernel<<<(N + 127) / 128, 256, 0, stream>>>(agg_bf, msg_wt, wt_pa + 16384,
                                                    a_b, skip, h, nullptr, h, h_bf, N);

    // ---- layer 1 (MLP only for the gathered rows; writes d_out directly) ----
    gemm_bf16<<<g768, 256, 0, stream>>>(h_bf, qkvw + 98304, fbias + 768, nullptr, qkv_bf,
                                        N, 128, 768, 3);
    agg_fused_kernel<<<N, 256, 0, stream>>>(qkv_bf, off4, pack, agg_bf, N);
    mlp_kernel<<<(MOUT + 127) / 128, 256, 0, stream>>>(agg_bf, msg_wt + 65536,
                                                       wt_pa + 2 * 16384, a_b + 128,
                                                       skip + 1, h, idx, out, nullptr, MOUT);
}

// Round 9
// 441.892 us; speedup vs baseline: 1.2761x; 1.2761x over previous
//
#include <hip/hip_runtime.h>
#include <math.h>

#define NN 50000
#define EE 600000
#define MOUT 10000
#define DEGCAP 384
#define NT4 (NN * 4)

typedef short bf16x8 __attribute__((ext_vector_type(8)));
typedef float f32x4 __attribute__((ext_vector_type(4)));

__device__ __forceinline__ unsigned short f2bf(float x) {
    unsigned int u = __float_as_uint(x);
    u = (u + 0x7FFFu + ((u >> 16) & 1u)) >> 16;
    return (unsigned short)u;
}
__device__ __forceinline__ float bf2f(unsigned int b) {
    return __uint_as_float(b << 16);
}

// ============ merged weight prep + x cast + CSR/stats zeroing ============
// qkv weight rows 512..767 PERMUTED (8B kv gathers); qrel rows pre-scaled by p_rel/sqrt(32).
__global__ __launch_bounds__(256) void prep_kernel(
    const float* __restrict__ proj_w, const float* __restrict__ a_w,
    const float* __restrict__ q_w, const float* __restrict__ q_b,
    const float* __restrict__ a_rel,
    const float* __restrict__ k_w, const float* __restrict__ k_b,
    const float* __restrict__ v_w, const float* __restrict__ v_b,
    const float* __restrict__ m_rel, const float* __restrict__ p_rel,
    const float* __restrict__ x,
    unsigned short* __restrict__ wt_pa, unsigned short* __restrict__ qkvw,
    float* __restrict__ fbias, unsigned short* __restrict__ msg_wt,
    unsigned short* __restrict__ x_bf, int* __restrict__ cnt,
    float* __restrict__ stats)
{
    const int b = blockIdx.x, t = threadIdx.x;
    if (b < 192) {                       // proj^T, a_w0^T, a_w1^T
        int wi = b >> 6;
        int flat = (b & 63) * 256 + t;
        int n = flat >> 7, c = flat & 127;
        const float* src = (wi == 0) ? proj_w : (wi == 1) ? a_w : a_w + 16384;
        wt_pa[(size_t)wi * 16384 + n * 128 + c] = f2bf(src[c * 128 + n]);
    } else if (b < 960) {                // fused qkv weight [768][128] per layer
        int q = b - 192;
        int l = q >= 384 ? 1 : 0;
        int flat = (q - l * 384) * 256 + t;
        int nrow = flat >> 7, c = flat & 127;
        unsigned short* wt = qkvw + (size_t)l * 98304;
        float* fb = fbias + l * 768;
        if (nrow < 512) {
            int r = nrow >> 7, hh = (nrow >> 5) & 3, d = nrow & 31;
            float prl = p_rel[l * 16 + r * 4 + hh] * 0.17677669529663687f;
            const float* qwc = q_w + (size_t)l * 16384 + c * 128 + hh * 32;
            const float* ar  = a_rel + (size_t)(l * 4 + r) * 4096 + hh * 1024 + d * 32;
            float s = 0.f;
            #pragma unroll 8
            for (int e = 0; e < 32; ++e) s += qwc[e] * ar[e];
            wt[(size_t)nrow * 128 + c] = f2bf(s * prl);
            if (c == 0) {
                const float* qb = q_b + l * 128 + hh * 32;
                float bb = 0.f;
                #pragma unroll 8
                for (int e = 0; e < 32; ++e) bb += qb[e] * ar[e];
                fb[nrow] = bb * prl;
            }
        } else {                         // k/v interleaved rows
            int j = nrow - 512;
            int tt = j >> 2, s = j & 3;
            int col = 2 * tt + (s & 1);
            const float* w  = (s < 2) ? k_w : v_w;
            const float* bb = (s < 2) ? k_b : v_b;
            wt[(size_t)nrow * 128 + c] = f2bf(w[(size_t)l * 16384 + c * 128 + col]);
            if (c == 0) fb[nrow] = bb[l * 128 + col];
        }
    } else if (b < 1472) {               // msg weight [128][512] per layer
        int q = b - 960;
        int l = q >= 256 ? 1 : 0;
        int flat = (q - l * 256) * 256 + t;
        int n = flat >> 9, kk = flat & 511;
        int h = n >> 5, e = n & 31;
        int r = kk >> 7, h2 = (kk >> 5) & 3, d = kk & 31;
        float val = (h2 == h) ? m_rel[(size_t)(l * 4 + r) * 4096 + h * 1024 + d * 32 + e] : 0.f;
        msg_wt[(size_t)l * 65536 + (size_t)n * 512 + kk] = f2bf(val);
    } else if (b < 7722) {               // cast x -> bf16
        int i = (b - 1472) * 256 + t;
        if (i < NN * 32) {
            float4 v = ((const float4*)x)[i];
            uint2 pk;
            pk.x = (unsigned int)f2bf(v.x) | ((unsigned int)f2bf(v.y) << 16);
            pk.y = (unsigned int)f2bf(v.z) | ((unsigned int)f2bf(v.w) << 16);
            ((uint2*)x_bf)[i] = pk;
        }
    } else {                             // zero cnt + stats
        int i = (b - 7722) * 256 + t;
        if (i < NT4) cnt[i] = 0;
        if (i < 256) stats[i] = 0.f;
    }
}

// ============ CSR build ============
__global__ __launch_bounds__(256) void hist_kernel(const int* __restrict__ ei,
    const int* __restrict__ et, int* __restrict__ cnt, int E)
{
    int e = blockIdx.x * 256 + threadIdx.x;
    if (e < E) atomicAdd(&cnt[ei[E + e] * 4 + et[e]], 1);
}

__global__ __launch_bounds__(256) void scan_block_kernel(const int* __restrict__ cnt,
    int* __restrict__ excl, int* __restrict__ bsum, int n)
{
    __shared__ int tmp[256];
    int i = blockIdx.x * 256 + threadIdx.x;
    int v = (i < n) ? cnt[i] : 0;
    tmp[threadIdx.x] = v;
    __syncthreads();
    for (int ofs = 1; ofs < 256; ofs <<= 1) {
        int t = (threadIdx.x >= ofs) ? tmp[threadIdx.x - ofs] : 0;
        __syncthreads();
        tmp[threadIdx.x] += t;
        __syncthreads();
    }
    if (i < n) excl[i] = tmp[threadIdx.x] - v;
    if (threadIdx.x == 255) bsum[blockIdx.x] = tmp[255];
}

// per-block prefix over bsum (no serial 1-block kernel, no grid sync)
__global__ __launch_bounds__(256) void scan_add_kernel(int* __restrict__ excl,
    const int* __restrict__ bsum, int* __restrict__ fill, int n, int total)
{
    __shared__ int red[256];
    const int b = blockIdx.x;
    int partial = 0;
    for (int j = threadIdx.x; j < b; j += 256) partial += bsum[j];
    red[threadIdx.x] = partial;
    __syncthreads();
    for (int ofs = 128; ofs > 0; ofs >>= 1) {
        if (threadIdx.x < ofs) red[threadIdx.x] += red[threadIdx.x + ofs];
        __syncthreads();
    }
    int prefix = red[0];
    int i = b * 256 + threadIdx.x;
    if (i < n) {
        int o = excl[i] + prefix;
        excl[i] = o;
        fill[i] = o;
    }
    if (b == 0 && threadIdx.x == 0) excl[n] = total;
}

__global__ __launch_bounds__(256) void scatter_kernel(const int* __restrict__ ei,
    const int* __restrict__ et, int* __restrict__ fill, int* __restrict__ pack, int E)
{
    int e = blockIdx.x * 256 + threadIdx.x;
    if (e >= E) return;
    int seg = ei[E + e] * 4 + et[e];
    int p = atomicAdd(&fill[seg], 1);
    pack[p] = ei[e];
}

// ============ proj GEMM + BN-stats epilogue: h_bf = x@projW + b; stats += (sum, sumsq) ============
__global__ __launch_bounds__(256) void projstats_kernel(
    const unsigned short* __restrict__ A, const unsigned short* __restrict__ Wt,
    const float* __restrict__ bias, unsigned short* __restrict__ Cb,
    float* __restrict__ stats, int M)
{
    __shared__ unsigned short As[128 * 40];
    __shared__ unsigned short Bs[128 * 40];
    const int t = threadIdx.x;
    const int wave = t >> 6, lane = t & 63;
    const int quad = lane >> 4, l16 = lane & 15;
    const int row0 = blockIdx.x * 128;
    const int wr = (wave & 1) * 64, wc = (wave >> 1) * 64;
    const int sr = t >> 1, sc = (t & 1) * 16;
    const int grow = row0 + sr;

    f32x4 acc[4][4];
    #pragma unroll
    for (int i = 0; i < 4; ++i)
        #pragma unroll
        for (int j = 0; j < 4; ++j)
            acc[i][j] = (f32x4){0.f, 0.f, 0.f, 0.f};

    uint4 av0 = make_uint4(0,0,0,0), av1 = av0, bv0, bv1;
    if (grow < M) {
        const uint4* ap = (const uint4*)(A + (size_t)grow * 128 + sc);
        av0 = ap[0]; av1 = ap[1];
    }
    {
        const uint4* bp = (const uint4*)(Wt + (size_t)sr * 128 + sc);
        bv0 = bp[0]; bv1 = bp[1];
    }
    for (int it = 0; it < 4; ++it) {
        __syncthreads();
        *(uint4*)(As + sr * 40 + sc)     = av0;
        *(uint4*)(As + sr * 40 + sc + 8) = av1;
        *(uint4*)(Bs + sr * 40 + sc)     = bv0;
        *(uint4*)(Bs + sr * 40 + sc + 8) = bv1;
        __syncthreads();
        if (it + 1 < 4) {
            int kb = (it + 1) * 32;
            if (grow < M) {
                const uint4* ap = (const uint4*)(A + (size_t)grow * 128 + kb + sc);
                av0 = ap[0]; av1 = ap[1];
            }
            const uint4* bp = (const uint4*)(Wt + (size_t)sr * 128 + kb + sc);
            bv0 = bp[0]; bv1 = bp[1];
        }
        bf16x8 af[4], bfr[4];
        #pragma unroll
        for (int f = 0; f < 4; ++f) {
            af[f]  = *(const bf16x8*)(As + (wr + f * 16 + l16) * 40 + quad * 8);
            bfr[f] = *(const bf16x8*)(Bs + (wc + f * 16 + l16) * 40 + quad * 8);
        }
        #pragma unroll
        for (int fr = 0; fr < 4; ++fr)
            #pragma unroll
            for (int fc = 0; fc < 4; ++fc)
                acc[fr][fc] = __builtin_amdgcn_mfma_f32_16x16x32_bf16(
                    af[fr], bfr[fc], acc[fr][fc], 0, 0, 0);
    }

    #pragma unroll
    for (int fc = 0; fc < 4; ++fc) {
        const int col = wc + fc * 16 + l16;
        const float bv = bias[col];
        float s = 0.f, s2 = 0.f;
        #pragma unroll
        for (int fr = 0; fr < 4; ++fr)
            #pragma unroll
            for (int reg = 0; reg < 4; ++reg) {
                int row = row0 + wr + fr * 16 + quad * 4 + reg;
                float val = acc[fr][fc][reg] + bv;
                if (row < M) {
                    Cb[(size_t)row * 128 + col] = f2bf(val);
                    s += val; s2 += val * val;
                }
            }
        s  += __shfl_xor(s, 16);  s  += __shfl_xor(s, 32);
        s2 += __shfl_xor(s2, 16); s2 += __shfl_xor(s2, 32);
        if (quad == 0) {
            atomicAdd(&stats[col], s);
            atomicAdd(&stats[128 + col], s2);
        }
    }
}

// ============ BN-apply + qkv0 GEMM: hn = BN(h); qkv = hn @ qkvw^T + fbias ============
__global__ __launch_bounds__(256) void bnqkv_kernel(
    const unsigned short* __restrict__ hb, const float* __restrict__ stats,
    const float* __restrict__ gamma, const float* __restrict__ beta,
    const unsigned short* __restrict__ qkvw, const float* __restrict__ fbias,
    unsigned short* __restrict__ hn, unsigned short* __restrict__ qkv, int M)
{
    __shared__ unsigned short hS[128 * 136];
    __shared__ unsigned short Bs[128 * 40];
    __shared__ float mulS[128], addS[128];
    const int t = threadIdx.x;
    const int row0 = blockIdx.x * 128;
    if (t < 128) {
        float invN = 1.f / 50000.f;
        float mu = stats[t] * invN;
        float var = stats[128 + t] * invN - mu * mu;
        float ml = rsqrtf(var + 1e-5f) * gamma[t];
        mulS[t] = ml;
        addS[t] = beta[t] - mu * ml;
    }
    __syncthreads();
    #pragma unroll
    for (int u = 0; u < 8; ++u) {
        int li = t + u * 256;                 // uint4 index; 16 per row
        int row = li >> 4, c0 = (li & 15) * 8;
        uint4 pk = make_uint4(0, 0, 0, 0);
        if (row0 + row < M)
            pk = ((const uint4*)(hb + (size_t)(row0 + row) * 128))[li & 15];
        unsigned int w[4] = {pk.x, pk.y, pk.z, pk.w};
        uint4 o;
        unsigned int ov[4];
        #pragma unroll
        for (int g = 0; g < 4; ++g) {
            int c = c0 + g * 2;
            float a0 = bf2f(w[g] & 0xFFFFu) * mulS[c]     + addS[c];
            float a1 = bf2f(w[g] >> 16)     * mulS[c + 1] + addS[c + 1];
            ov[g] = (unsigned int)f2bf(a0) | ((unsigned int)f2bf(a1) << 16);
        }
        o.x = ov[0]; o.y = ov[1]; o.z = ov[2]; o.w = ov[3];
        *(uint4*)(hS + row * 136 + c0) = o;
        if (row0 + row < M)
            ((uint4*)(hn + (size_t)(row0 + row) * 128))[li & 15] = o;
    }
    __syncthreads();

    const int wave = t >> 6, lane = t & 63;
    const int quad = lane >> 4, l16 = lane & 15;
    const int wr = (wave & 1) * 64, wcl = (wave >> 1) * 64;
    const int sr = t >> 1, scc = (t & 1) * 16;
    for (int ch = 0; ch < 6; ++ch) {
        f32x4 acc[4][4];
        #pragma unroll
        for (int i = 0; i < 4; ++i)
            #pragma unroll
            for (int j = 0; j < 4; ++j)
                acc[i][j] = (f32x4){0.f, 0.f, 0.f, 0.f};
        for (int it = 0; it < 4; ++it) {
            __syncthreads();
            const uint4* bp = (const uint4*)(qkvw + (size_t)(ch * 128 + sr) * 128 + it * 32 + scc);
            *(uint4*)(Bs + sr * 40 + scc)     = bp[0];
            *(uint4*)(Bs + sr * 40 + scc + 8) = bp[1];
            __syncthreads();
            bf16x8 af[4], bfr[4];
            #pragma unroll
            for (int f = 0; f < 4; ++f) {
                af[f]  = *(const bf16x8*)(hS + (wr + f * 16 + l16) * 136 + it * 32 + quad * 8);
                bfr[f] = *(const bf16x8*)(Bs + (wcl + f * 16 + l16) * 40 + quad * 8);
            }
            #pragma unroll
            for (int fr = 0; fr < 4; ++fr)
                #pragma unroll
                for (int fc = 0; fc < 4; ++fc)
                    acc[fr][fc] = __builtin_amdgcn_mfma_f32_16x16x32_bf16(
                        af[fr], bfr[fc], acc[fr][fc], 0, 0, 0);
        }
        float b4[4];
        #pragma unroll
        for (int fc = 0; fc < 4; ++fc)
            b4[fc] = fbias[ch * 128 + wcl + fc * 16 + l16];
        #pragma unroll
        for (int fr = 0; fr < 4; ++fr)
            #pragma unroll
            for (int reg = 0; reg < 4; ++reg) {
                int row = row0 + wr + fr * 16 + quad * 4 + reg;
                if (row >= M) continue;
                #pragma unroll
                for (int fc = 0; fc < 4; ++fc) {
                    int col = ch * 128 + wcl + fc * 16 + l16;
                    qkv[(size_t)row * 768 + col] = f2bf(acc[fr][fc][reg] + b4[fc]);
                }
            }
    }
}

// ============ fused attention: per-node wave, 4 sorted runs, unroll-4, 8B kv (R6 shape) ============
__global__ __launch_bounds__(256) void agg_fused_kernel(
    const unsigned short* __restrict__ qkv,
    const int* __restrict__ off4, const int* __restrict__ pack,
    const int* __restrict__ rowmap, unsigned short* __restrict__ aggb, int count)
{
    __shared__ int spack[4][DEGCAP];
    const int wv = threadIdx.x >> 6;
    const int lane = threadIdx.x & 63;
    const int unit = blockIdx.x * 4 + wv;
    if (unit >= count) return;                 // no __syncthreads in this kernel
    const int node = rowmap ? __builtin_amdgcn_readfirstlane(rowmap[unit]) : unit;

    int off_r[5];
    #pragma unroll
    for (int i = 0; i < 5; ++i)
        off_r[i] = __builtin_amdgcn_readfirstlane(off4[node * 4 + i]);
    const int beg = off_r[0];
    const int deg = off_r[4] - beg;
    const bool cached = deg <= DEGCAP;

    const unsigned int* qrow = (const unsigned int*)(qkv + (size_t)node * 768);

    if (cached) {
        for (int i = lane; i < deg; i += 64) spack[wv][i] = pack[beg + i];
        asm volatile("s_waitcnt vmcnt(0) lgkmcnt(0)" ::: "memory");
    }

    unsigned int outw[4];
    for (int r = 0; r < 4; ++r) {
        unsigned int qu = qrow[r * 64 + lane];
        float qx = bf2f(qu & 0xFFFFu);          // pre-scaled by p_rel/sqrt(32)
        float qy = bf2f(qu >> 16);
        float den = 0.f, ax = 0.f, ay = 0.f;

        if (cached) {
            const int rb = off_r[r] - beg, re = off_r[r + 1] - beg;
            for (int i = rb; i < re; i += 4) {
                unsigned int ku[4], vu[4];
                #pragma unroll
                for (int j = 0; j < 4; ++j) {
                    int ii = i + j; if (ii >= re) ii = re - 1;
                    int src = spack[wv][ii];
                    uint2 kv = *(const uint2*)(qkv + (size_t)src * 768 + 512 + lane * 4);
                    ku[j] = kv.x; vu[j] = kv.y;
                }
                float p[4];
                #pragma unroll
                for (int j = 0; j < 4; ++j)
                    p[j] = qx * bf2f(ku[j] & 0xFFFFu) + qy * bf2f(ku[j] >> 16);
                #pragma unroll
                for (int j = 0; j < 4; ++j) {
                    p[j] += __shfl_xor(p[j], 1); p[j] += __shfl_xor(p[j], 2);
                    p[j] += __shfl_xor(p[j], 4); p[j] += __shfl_xor(p[j], 8);
                }
                #pragma unroll
                for (int j = 0; j < 4; ++j) {
                    float s = fminf(fmaxf(p[j], -80.f), 80.f);
                    float e = __expf(s);
                    if (i + j >= re) e = 0.f;
                    den += e;
                    ax += e * bf2f(vu[j] & 0xFFFFu);
                    ay += e * bf2f(vu[j] >> 16);
                }
            }
        } else {   // giant-degree fallback
            for (int pp = off_r[r]; pp < off_r[r + 1]; ++pp) {
                int src = __builtin_amdgcn_readfirstlane(pack[pp]);
                uint2 kv = *(const uint2*)(qkv + (size_t)src * 768 + 512 + lane * 4);
                float p0 = qx * bf2f(kv.x & 0xFFFFu) + qy * bf2f(kv.x >> 16);
                p0 += __shfl_xor(p0, 1); p0 += __shfl_xor(p0, 2);
                p0 += __shfl_xor(p0, 4); p0 += __shfl_xor(p0, 8);
                float e = __expf(fminf(fmaxf(p0, -80.f), 80.f));
                den += e;
                ax += e * bf2f(kv.y & 0xFFFFu);
                ay += e * bf2f(kv.y >> 16);
            }
        }
        float inv = den > 0.f ? 1.f / den : 0.f;
        outw[r] = (unsigned int)f2bf(ax * inv) | ((unsigned int)f2bf(ay * inv) << 16);
    }
    unsigned int* op = (unsigned int*)(aggb + (size_t)unit * 512);
    #pragma unroll
    for (int r = 0; r < 4; ++r) op[r * 64 + lane] = outw[r];
}

// ============ layer-0 MLP + qkv1: h1 = gate*(gelu(agg@W3)@AW + b) + (1-g)*hn; qkv1 = h1 @ qkvw1 ============
__global__ __launch_bounds__(256) void mlpqkv_kernel(
    const unsigned short* __restrict__ A, const unsigned short* __restrict__ W3t,
    const unsigned short* __restrict__ AWt, const float* __restrict__ a_bias,
    const float* __restrict__ skipv, const unsigned short* __restrict__ hres,
    const unsigned short* __restrict__ qkvw1, const float* __restrict__ fbias1,
    unsigned short* __restrict__ h1, unsigned short* __restrict__ qkv, int M)
{
    __shared__ unsigned short As[128 * 40];
    __shared__ unsigned short Bs[128 * 40];
    __shared__ unsigned short msgS[128 * 136];
    const int t = threadIdx.x;
    const int wave = t >> 6, lane = t & 63;
    const int quad = lane >> 4, l16 = lane & 15;
    const int row0 = blockIdx.x * 128;
    const int wr = (wave & 1) * 64, wcl = (wave >> 1) * 64;
    const int sr = t >> 1, scc = (t & 1) * 16;
    const int grow = row0 + sr;
    const bool rvalid = grow < M;

    f32x4 acc[4][4];
    #pragma unroll
    for (int i = 0; i < 4; ++i)
        #pragma unroll
        for (int j = 0; j < 4; ++j)
            acc[i][j] = (f32x4){0.f, 0.f, 0.f, 0.f};

    uint4 av0 = make_uint4(0,0,0,0), av1 = av0, bv0, bv1;
    if (rvalid) {
        const uint4* ap = (const uint4*)(A + (size_t)grow * 512 + scc);
        av0 = ap[0]; av1 = ap[1];
    }
    {
        const uint4* bp = (const uint4*)(W3t + (size_t)sr * 512 + scc);
        bv0 = bp[0]; bv1 = bp[1];
    }
    for (int it = 0; it < 16; ++it) {           // stage 1: K = 512
        __syncthreads();
        *(uint4*)(As + sr * 40 + scc)     = av0;
        *(uint4*)(As + sr * 40 + scc + 8) = av1;
        *(uint4*)(Bs + sr * 40 + scc)     = bv0;
        *(uint4*)(Bs + sr * 40 + scc + 8) = bv1;
        __syncthreads();
        if (it + 1 < 16) {
            int kb = (it + 1) * 32;
            if (rvalid) {
                const uint4* ap = (const uint4*)(A + (size_t)grow * 512 + kb + scc);
                av0 = ap[0]; av1 = ap[1];
            }
            const uint4* bp = (const uint4*)(W3t + (size_t)sr * 512 + kb + scc);
            bv0 = bp[0]; bv1 = bp[1];
        }
        bf16x8 af[4], bfr[4];
        #pragma unroll
        for (int f = 0; f < 4; ++f) {
            af[f]  = *(const bf16x8*)(As + (wr + f * 16 + l16) * 40 + quad * 8);
            bfr[f] = *(const bf16x8*)(Bs + (wcl + f * 16 + l16) * 40 + quad * 8);
        }
        #pragma unroll
        for (int fr = 0; fr < 4; ++fr)
            #pragma unroll
            for (int fc = 0; fc < 4; ++fc)
                acc[fr][fc] = __builtin_amdgcn_mfma_f32_16x16x32_bf16(
                    af[fr], bfr[fc], acc[fr][fc], 0, 0, 0);
    }

    // gelu -> msgS
    #pragma unroll
    for (int fr = 0; fr < 4; ++fr)
        #pragma unroll
        for (int reg = 0; reg < 4; ++reg) {
            int rl = wr + fr * 16 + quad * 4 + reg;
            #pragma unroll
            for (int fc = 0; fc < 4; ++fc) {
                int col = wcl + fc * 16 + l16;
                float v = acc[fr][fc][reg];
                float gl = 0.5f * v * (1.f + erff(v * 0.70710678118654752f));
                msgS[rl * 136 + col] = f2bf(gl);
            }
        }

    // stage 2: K = 128 from msgS vs AWt
    f32x4 acc2[4][4];
    #pragma unroll
    for (int i = 0; i < 4; ++i)
        #pragma unroll
        for (int j = 0; j < 4; ++j)
            acc2[i][j] = (f32x4){0.f, 0.f, 0.f, 0.f};
    for (int it = 0; it < 4; ++it) {
        __syncthreads();
        const uint4* bp = (const uint4*)(AWt + (size_t)sr * 128 + it * 32 + scc);
        *(uint4*)(Bs + sr * 40 + scc)     = bp[0];
        *(uint4*)(Bs + sr * 40 + scc + 8) = bp[1];
        __syncthreads();
        bf16x8 af[4], bfr[4];
        #pragma unroll
        for (int f = 0; f < 4; ++f) {
            af[f]  = *(const bf16x8*)(msgS + (wr + f * 16 + l16) * 136 + it * 32 + quad * 8);
            bfr[f] = *(const bf16x8*)(Bs + (wcl + f * 16 + l16) * 40 + quad * 8);
        }
        #pragma unroll
        for (int fr = 0; fr < 4; ++fr)
            #pragma unroll
            for (int fc = 0; fc < 4; ++fc)
                acc2[fr][fc] = __builtin_amdgcn_mfma_f32_16x16x32_bf16(
                    af[fr], bfr[fc], acc2[fr][fc], 0, 0, 0);
    }

    const float gate = 1.f / (1.f + __expf(-skipv[0]));
    __syncthreads();                            // all stage-2 msgS reads complete
    #pragma unroll
    for (int fr = 0; fr < 4; ++fr)
        #pragma unroll
        for (int reg = 0; reg < 4; ++reg) {
            int rl = wr + fr * 16 + quad * 4 + reg;
            int row = row0 + rl;
            #pragma unroll
            for (int fc = 0; fc < 4; ++fc) {
                int col = wcl + fc * 16 + l16;
                float val = acc2[fr][fc][reg] + a_bias[col];
                float nv = val;
                if (row < M) {
                    unsigned int hu = hres[(size_t)row * 128 + col];
                    nv = gate * val + (1.f - gate) * bf2f(hu);
                    h1[(size_t)row * 128 + col] = f2bf(nv);
                }
                msgS[rl * 136 + col] = f2bf(nv);   // h1 tile for stage 3
            }
        }

    // stage 3: qkv1 = h1 @ qkvw1^T (6 col chunks, K = 128 from msgS)
    for (int ch = 0; ch < 6; ++ch) {
        f32x4 acc3[4][4];
        #pragma unroll
        for (int i = 0; i < 4; ++i)
            #pragma unroll
            for (int j = 0; j < 4; ++j)
                acc3[i][j] = (f32x4){0.f, 0.f, 0.f, 0.f};
        for (int it = 0; it < 4; ++it) {
            __syncthreads();
            const uint4* bp = (const uint4*)(qkvw1 + (size_t)(ch * 128 + sr) * 128 + it * 32 + scc);
            *(uint4*)(Bs + sr * 40 + scc)     = bp[0];
            *(uint4*)(Bs + sr * 40 + scc + 8) = bp[1];
            __syncthreads();
            bf16x8 af[4], bfr[4];
            #pragma unroll
            for (int f = 0; f < 4; ++f) {
                af[f]  = *(const bf16x8*)(msgS + (wr + f * 16 + l16) * 136 + it * 32 + quad * 8);
                bfr[f] = *(const bf16x8*)(Bs + (wcl + f * 16 + l16) * 40 + quad * 8);
            }
            #pragma unroll
            for (int fr = 0; fr < 4; ++fr)
                #pragma unroll
                for (int fc = 0; fc < 4; ++fc)
                    acc3[fr][fc] = __builtin_amdgcn_mfma_f32_16x16x32_bf16(
                        af[fr], bfr[fc], acc3[fr][fc], 0, 0, 0);
        }
        float b4[4];
        #pragma unroll
        for (int fc = 0; fc < 4; ++fc)
            b4[fc] = fbias1[ch * 128 + wcl + fc * 16 + l16];
        #pragma unroll
        for (int fr = 0; fr < 4; ++fr)
            #pragma unroll
            for (int reg = 0; reg < 4; ++reg) {
                int row = row0 + wr + fr * 16 + quad * 4 + reg;
                if (row >= M) continue;
                #pragma unroll
                for (int fc = 0; fc < 4; ++fc) {
                    int col = ch * 128 + wcl + fc * 16 + l16;
                    qkv[(size_t)row * 768 + col] = f2bf(acc3[fr][fc][reg] + b4[fc]);
                }
            }
    }
}

// ============ layer-1 MLP (compact rows): out = gate*(...) + (1-g)*h1[idx] ============
__global__ __launch_bounds__(256) void mlp1_kernel(
    const unsigned short* __restrict__ A, const unsigned short* __restrict__ W3t,
    const unsigned short* __restrict__ AWt, const float* __restrict__ a_bias,
    const float* __restrict__ skipv, const unsigned short* __restrict__ hres,
    const int* __restrict__ rowmap, float* __restrict__ out, int M)
{
    __shared__ unsigned short As[128 * 40];
    __shared__ unsigned short Bs[128 * 40];
    __shared__ unsigned short msgS[128 * 136];
    const int t = threadIdx.x;
    const int wave = t >> 6, lane = t & 63;
    const int quad = lane >> 4, l16 = lane & 15;
    const int row0 = blockIdx.x * 128;
    const int wr = (wave & 1) * 64, wcl = (wave >> 1) * 64;
    const int sr = t >> 1, scc = (t & 1) * 16;
    const int grow = row0 + sr;
    const bool rvalid = grow < M;

    f32x4 acc[4][4];
    #pragma unroll
    for (int i = 0; i < 4; ++i)
        #pragma unroll
        for (int j = 0; j < 4; ++j)
            acc[i][j] = (f32x4){0.f, 0.f, 0.f, 0.f};

    uint4 av0 = make_uint4(0,0,0,0), av1 = av0, bv0, bv1;
    if (rvalid) {
        const uint4* ap = (const uint4*)(A + (size_t)grow * 512 + scc);
        av0 = ap[0]; av1 = ap[1];
    }
    {
        const uint4* bp = (const uint4*)(W3t + (size_t)sr * 512 + scc);
        bv0 = bp[0]; bv1 = bp[1];
    }
    for (int it = 0; it < 16; ++it) {
        __syncthreads();
        *(uint4*)(As + sr * 40 + scc)     = av0;
        *(uint4*)(As + sr * 40 + scc + 8) = av1;
        *(uint4*)(Bs + sr * 40 + scc)     = bv0;
        *(uint4*)(Bs + sr * 40 + scc + 8) = bv1;
        __syncthreads();
        if (it + 1 < 16) {
            int kb = (it + 1) * 32;
            if (rvalid) {
                const uint4* ap = (const uint4*)(A + (size_t)grow * 512 + kb + scc);
                av0 = ap[0]; av1 = ap[1];
            }
            const uint4* bp = (const uint4*)(W3t + (size_t)sr * 512 + kb + scc);
            bv0 = bp[0]; bv1 = bp[1];
        }
        bf16x8 af[4], bfr[4];
        #pragma unroll
        for (int f = 0; f < 4; ++f) {
            af[f]  = *(const bf16x8*)(As + (wr + f * 16 + l16) * 40 + quad * 8);
            bfr[f] = *(const bf16x8*)(Bs + (wcl + f * 16 + l16) * 40 + quad * 8);
        }
        #pragma unroll
        for (int fr = 0; fr < 4; ++fr)
            #pragma unroll
            for (int fc = 0; fc < 4; ++fc)
                acc[fr][fc] = __builtin_amdgcn_mfma_f32_16x16x32_bf16(
                    af[fr], bfr[fc], acc[fr][fc], 0, 0, 0);
    }

    #pragma unroll
    for (int fr = 0; fr < 4; ++fr)
        #pragma unroll
        for (int reg = 0; reg < 4; ++reg) {
            int rl = wr + fr * 16 + quad * 4 + reg;
            #pragma unroll
            for (int fc = 0; fc < 4; ++fc) {
                int col = wcl + fc * 16 + l16;
                float v = acc[fr][fc][reg];
                float gl = 0.5f * v * (1.f + erff(v * 0.70710678118654752f));
                msgS[rl * 136 + col] = f2bf(gl);
            }
        }

    f32x4 acc2[4][4];
    #pragma unroll
    for (int i = 0; i < 4; ++i)
        #pragma unroll
        for (int j = 0; j < 4; ++j)
            acc2[i][j] = (f32x4){0.f, 0.f, 0.f, 0.f};
    for (int it = 0; it < 4; ++it) {
        __syncthreads();
        const uint4* bp = (const uint4*)(AWt + (size_t)sr * 128 + it * 32 + scc);
        *(uint4*)(Bs + sr * 40 + scc)     = bp[0];
        *(uint4*)(Bs + sr * 40 + scc + 8) = bp[1];
        __syncthreads();
        bf16x8 af[4], bfr[4];
        #pragma unroll
        for (int f = 0; f < 4; ++f) {
            af[f]  = *(const bf16x8*)(msgS + (wr + f * 16 + l16) * 136 + it * 32 + quad * 8);
            bfr[f] = *(const bf16x8*)(Bs + (wcl + f * 16 + l16) * 40 + quad * 8);
        }
        #pragma unroll
        for (int fr = 0; fr < 4; ++fr)
            #pragma unroll
            for (int fc = 0; fc < 4; ++fc)
                acc2[fr][fc] = __builtin_amdgcn_mfma_f32_16x16x32_bf16(
                    af[fr], bfr[fc], acc2[fr][fc], 0, 0, 0);
    }

    const float gate = 1.f / (1.f + __expf(-skipv[0]));
    #pragma unroll
    for (int fr = 0; fr < 4; ++fr)
        #pragma unroll
        for (int reg = 0; reg < 4; ++reg) {
            int row = row0 + wr + fr * 16 + quad * 4 + reg;
            if (row >= M) continue;
            int hrow = rowmap[row];
            #pragma unroll
            for (int fc = 0; fc < 4; ++fc) {
                int col = wcl + fc * 16 + l16;
                float val = acc2[fr][fc][reg] + a_bias[col];
                float nv = gate * val + (1.f - gate) * bf2f((unsigned int)hres[(size_t)hrow * 128 + col]);
                out[(size_t)row * 128 + col] = nv;
            }
        }
}

extern "C" void kernel_launch(void* const* d_in, const int* in_sizes, int n_in,
                              void* d_out, int out_size, void* d_ws, size_t ws_size,
                              hipStream_t stream)
{
    const float* x      = (const float*)d_in[0];
    const float* proj_w = (const float*)d_in[1];
    const float* proj_b = (const float*)d_in[2];
    const float* bn_g   = (const float*)d_in[3];
    const float* bn_b   = (const float*)d_in[4];
    const float* q_w    = (const float*)d_in[5];
    const float* q_b    = (const float*)d_in[6];
    const float* k_w    = (const float*)d_in[7];
    const float* k_b    = (const float*)d_in[8];
    const float* v_w    = (const float*)d_in[9];
    const float* v_b    = (const float*)d_in[10];
    const float* a_w    = (const float*)d_in[11];
    const float* a_b    = (const float*)d_in[12];
    const float* skip   = (const float*)d_in[13];
    const float* a_rel  = (const float*)d_in[14];
    const float* m_rel  = (const float*)d_in[15];
    const float* p_rel  = (const float*)d_in[16];
    const int* edge_index = (const int*)d_in[17];
    const int* edge_type  = (const int*)d_in[18];
    const int* idx        = (const int*)d_in[19];
    float* out = (float*)d_out;

    const int N = NN, E = EE;
    float* ws = (float*)d_ws;
    size_t o = 0;
    float* stats  = ws + o;  o += 256;
    float* fbias  = ws + o;  o += 2 * 768;
    int* cnt  = (int*)(ws + o); o += NT4;
    int* off4 = (int*)(ws + o); o += NT4 + 1;
    int* fill = (int*)(ws + o); o += NT4;
    int* bsum = (int*)(ws + o); o += 1024;
    int* pack = (int*)(ws + o); o += E;
    unsigned short* x_bf   = (unsigned short*)(ws + o); o += (size_t)N * 64;
    unsigned short* h_bf   = (unsigned short*)(ws + o); o += (size_t)N * 64;
    unsigned short* hn_bf  = (unsigned short*)(ws + o); o += (size_t)N * 64;
    unsigned short* h1_bf  = (unsigned short*)(ws + o); o += (size_t)N * 64;
    unsigned short* qkv_bf = (unsigned short*)(ws + o); o += (size_t)N * 384;
    unsigned short* agg_bf = (unsigned short*)(ws + o); o += (size_t)N * 256;
    unsigned short* wt_pa  = (unsigned short*)(ws + o); o += 3 * 16384 / 2;
    unsigned short* qkvw   = (unsigned short*)(ws + o); o += 2 * 98304 / 2;
    unsigned short* msg_wt = (unsigned short*)(ws + o); o += 2 * 65536 / 2;

    const int NB4 = (NT4 + 255) / 256;          // 782
    const int g = (N + 127) / 128;              // 391

    // 1) prep: weights, x cast, zero cnt/stats
    prep_kernel<<<7722 + NB4, 256, 0, stream>>>(
        proj_w, a_w, q_w, q_b, a_rel, k_w, k_b, v_w, v_b, m_rel, p_rel, x,
        wt_pa, qkvw, fbias, msg_wt, x_bf, cnt, stats);

    // 2-5) CSR build
    hist_kernel<<<(E + 255) / 256, 256, 0, stream>>>(edge_index, edge_type, cnt, E);
    scan_block_kernel<<<NB4, 256, 0, stream>>>(cnt, off4, bsum, NT4);
    scan_add_kernel<<<NB4, 256, 0, stream>>>(off4, bsum, fill, NT4, E);
    scatter_kernel<<<(E + 255) / 256, 256, 0, stream>>>(edge_index, edge_type, fill, pack, E);

    // 6) proj GEMM + BN stats
    projstats_kernel<<<g, 256, 0, stream>>>(x_bf, wt_pa, proj_b, h_bf, stats, N);

    // 7) BN apply + qkv0
    bnqkv_kernel<<<g, 256, 0, stream>>>(h_bf, stats, bn_g, bn_b, qkvw, fbias,
                                        hn_bf, qkv_bf, N);

    // 8) attention layer 0 (all nodes)
    agg_fused_kernel<<<(N + 3) / 4, 256, 0, stream>>>(qkv_bf, off4, pack, nullptr,
                                                      agg_bf, N);

    // 9) MLP0 + residual + qkv1
    mlpqkv_kernel<<<g, 256, 0, stream>>>(agg_bf, msg_wt, wt_pa + 16384, a_b, skip,
                                         hn_bf, qkvw + 98304, fbias + 768,
                                         h1_bf, qkv_bf, N);

    // 10) attention layer 1 (only the idx rows)
    agg_fused_kernel<<<(MOUT + 3) / 4, 256, 0, stream>>>(qkv_bf, off4, pack, idx,
                                                         agg_bf, MOUT);

    // 11) MLP1 + residual -> out
    mlp1_kernel<<<(MOUT + 127) / 128, 256, 0, stream>>>(agg_bf, msg_wt + 65536,
                                                        wt_pa + 2 * 16384, a_b + 128,
                                                        skip + 1, h1_bf, idx, out, MOUT);
}